// Round 10
// baseline (403.008 us; speedup 1.0000x reference)
//
#include <hip/hip_runtime.h>
#include <hip/hip_bf16.h>
#include <math.h>

#define Bn 64
#define Sn 512
#define Hn 1024
#define Tn 48

#define LOG2E 1.4426950408889634f
#define LN2f  0.6931471805599453f

#define PRED_OFF (Bn*Sn*Tn)
#define LOSS_OFF (PRED_OFF + Bn*Sn)

#define RL(x,i) __int_as_float(__builtin_amdgcn_readlane(__float_as_int(x),(i)))

#if __has_builtin(__builtin_amdgcn_exp2f)
#define EXP2(x) __builtin_amdgcn_exp2f(x)
#else
#define EXP2(x) exp2f(x)
#endif
#if __has_builtin(__builtin_amdgcn_logf)
#define LOG2(x) __builtin_amdgcn_logf(x)
#else
#define LOG2(x) log2f(x)
#endif

// Pin a value into a VGPR at this program point. Placed INSIDE the scan loop
// so spilling the table would cost a reload every iteration -> allocator keeps
// it resident.
#define PIN(x) asm volatile("" : "+v"(x))

__device__ __forceinline__ unsigned umin2(unsigned a, unsigned b) { return a < b ? a : b; }

// workspace layout (bytes): [0,256) logZ, [256,512) gold, [512, +6291456) v-values,
// then 1572864 bytes of backpointers.
#define VWS_BYTE_OFF 512
#define BPW_BYTE_OFF (512 + (size_t)Bn*Sn*Tn*4)

// ======================= GEMM: feat = x @ W + b =======================
// BM=128, 256 threads, per-thread 4 rows x 6 cols; rows ty+32p so the wave's
// a-reads hit 8 distinct banks (68-dword row stride: ty*68 % 32 = ty*4).
#define DOT4(ACC,A,B) { ACC = fmaf((A).x,(B).x,ACC); ACC = fmaf((A).y,(B).y,ACC); ACC = fmaf((A).z,(B).z,ACC); ACC = fmaf((A).w,(B).w,ACC); }

__global__ __launch_bounds__(256) void gemm_feat(
    const float* __restrict__ x, const float* __restrict__ W,
    const float* __restrict__ bias, float* __restrict__ feat)
{
  __shared__ __align__(16) float xs[128][68];
  __shared__ __align__(16) float wsT[Tn][68];
  const int tid = threadIdx.x;
  const int srow  = tid >> 1;        // 0..127 staging row
  const int shalf = tid & 1;         // which 32-float half
  const int ty = tid >> 3;           // 0..31 -> rows ty, ty+32, ty+64, ty+96
  const int tx = tid & 7;            // 0..7  -> cols tx*6 .. tx*6+5
  const size_t row0 = (size_t)blockIdx.x * 128;

  float4 xreg[8];
  float  wreg[12];
  #pragma unroll
  for (int p = 0; p < 8; ++p)
    xreg[p] = *reinterpret_cast<const float4*>(&x[(row0 + srow)*Hn + shalf*32 + p*4]);
  #pragma unroll
  for (int i = 0; i < 12; ++i) {
    const int id = tid + i*256; const int kk = id/Tn; const int t = id - kk*Tn;
    wreg[i] = W[(size_t)kk*Tn + t];
  }

  float acc[4][6];
  #pragma unroll
  for (int r = 0; r < 4; ++r)
    #pragma unroll
    for (int c = 0; c < 6; ++c) acc[r][c] = 0.f;

  for (int k0 = 0; k0 < Hn; k0 += 64) {
    #pragma unroll
    for (int p = 0; p < 8; ++p)
      *reinterpret_cast<float4*>(&xs[srow][shalf*32 + p*4]) = xreg[p];
    #pragma unroll
    for (int i = 0; i < 12; ++i) {
      const int id = tid + i*256; const int kk = id/Tn; const int t = id - kk*Tn;
      wsT[t][kk] = wreg[i];
    }
    __syncthreads();
    if (k0 + 64 < Hn) {
      #pragma unroll
      for (int p = 0; p < 8; ++p)
        xreg[p] = *reinterpret_cast<const float4*>(&x[(row0 + srow)*Hn + (k0+64) + shalf*32 + p*4]);
      #pragma unroll
      for (int i = 0; i < 12; ++i) {
        const int id = tid + i*256; const int kk = id/Tn; const int t = id - kk*Tn;
        wreg[i] = W[(size_t)(k0 + 64 + kk)*Tn + t];
      }
    }
    #pragma unroll 4
    for (int kk = 0; kk < 64; kk += 4) {
      const float4 a0 = *reinterpret_cast<const float4*>(&xs[ty +  0][kk]);
      const float4 a1 = *reinterpret_cast<const float4*>(&xs[ty + 32][kk]);
      const float4 a2 = *reinterpret_cast<const float4*>(&xs[ty + 64][kk]);
      const float4 a3 = *reinterpret_cast<const float4*>(&xs[ty + 96][kk]);
      const float4 w0 = *reinterpret_cast<const float4*>(&wsT[tx*6+0][kk]);
      const float4 w1 = *reinterpret_cast<const float4*>(&wsT[tx*6+1][kk]);
      const float4 w2 = *reinterpret_cast<const float4*>(&wsT[tx*6+2][kk]);
      const float4 w3 = *reinterpret_cast<const float4*>(&wsT[tx*6+3][kk]);
      const float4 w4 = *reinterpret_cast<const float4*>(&wsT[tx*6+4][kk]);
      const float4 w5 = *reinterpret_cast<const float4*>(&wsT[tx*6+5][kk]);
      DOT4(acc[0][0],a0,w0) DOT4(acc[0][1],a0,w1) DOT4(acc[0][2],a0,w2)
      DOT4(acc[0][3],a0,w3) DOT4(acc[0][4],a0,w4) DOT4(acc[0][5],a0,w5)
      DOT4(acc[1][0],a1,w0) DOT4(acc[1][1],a1,w1) DOT4(acc[1][2],a1,w2)
      DOT4(acc[1][3],a1,w3) DOT4(acc[1][4],a1,w4) DOT4(acc[1][5],a1,w5)
      DOT4(acc[2][0],a2,w0) DOT4(acc[2][1],a2,w1) DOT4(acc[2][2],a2,w2)
      DOT4(acc[2][3],a2,w3) DOT4(acc[2][4],a2,w4) DOT4(acc[2][5],a2,w5)
      DOT4(acc[3][0],a3,w0) DOT4(acc[3][1],a3,w1) DOT4(acc[3][2],a3,w2)
      DOT4(acc[3][3],a3,w3) DOT4(acc[3][4],a3,w4) DOT4(acc[3][5],a3,w5)
    }
    __syncthreads();
  }
  #pragma unroll
  for (int c = 0; c < 6; ++c) {
    const int col = tx*6 + c;
    const float bv = bias[col];
    #pragma unroll
    for (int r = 0; r < 4; ++r)
      feat[(row0 + ty + r*32)*Tn + col] = acc[r][c] + bv;
  }
}

// ============ helper: sequence length (prefix mask) per wave ============
__device__ __forceinline__ int seq_len(const int* __restrict__ mask, int b, int lane) {
  int lc = 0;
  #pragma unroll
  for (int it = 0; it < Sn/64; ++it) lc += (mask[(size_t)b*Sn + it*64 + lane] != 0);
  #pragma unroll
  for (int off = 32; off; off >>= 1) lc += __shfl_xor(lc, off);
  return lc;
}

// ======================= crf_scan: 192 single-wave blocks =======================
__global__ __launch_bounds__(64, 1) void crf_scan(
    const float* __restrict__ feat,
    const int* __restrict__ mask,
    const int* __restrict__ labels,
    const float* __restrict__ trans,
    const float* __restrict__ startv,
    const float* __restrict__ endv,
    float* __restrict__ vws,
    float* __restrict__ wsLogZ,
    float* __restrict__ wsGold)
{
  const int role = blockIdx.x >> 6;
  const int b    = blockIdx.x & 63;
  const int lane = threadIdx.x;
  const float* fb = feat + (size_t)b * Sn * Tn;
  const int len = seq_len(mask, b, lane);
  const int j = (lane < Tn) ? lane : (Tn - 1);

  if (role == 0) {
    // ---------------- log-partition (registers only) ----------------
    float Ev[48];
    #pragma unroll
    for (int i = 0; i < 48; ++i) Ev[i] = EXP2(trans[i*Tn + j] * LOG2E);
    float emq[8];
    #pragma unroll
    for (int d = 0; d < 8; ++d) {
      int s = 1 + d; s = s < len ? s : len - 1;
      emq[d] = fb[(size_t)s * Tn + j];
    }
    const float a0 = (startv[j] + fb[j]) * LOG2E;
    float Zref = RL(a0, 0);
    float beta = a0 - Zref;
    float p = EXP2(beta);
    for (int t = 1; t < len; t += 8) {
      #pragma unroll
      for (int i = 0; i < 48; ++i) PIN(Ev[i]);   // in-loop: forces residency
      #pragma unroll
      for (int u = 0; u < 8; ++u) {
        const int tt = t + u;
        if (tt < len) {
          const float em2 = emq[u] * LOG2E;
          int tf = tt + 8; tf = tf < len ? tf : len - 1;
          emq[u] = fb[(size_t)tf * Tn + j];
          float s0=0.f, s1=0.f, s2=0.f, s3=0.f;
          #pragma unroll
          for (int k = 0; k < 12; ++k) {
            s0 = fmaf(RL(p, 4*k+0), Ev[4*k+0], s0);
            s1 = fmaf(RL(p, 4*k+1), Ev[4*k+1], s1);
            s2 = fmaf(RL(p, 4*k+2), Ev[4*k+2], s2);
            s3 = fmaf(RL(p, 4*k+3), Ev[4*k+3], s3);
          }
          const float dj = LOG2((s0 + s1) + (s2 + s3)) + em2;
          const float d0 = RL(dj, 0);
          Zref += d0;
          beta = dj - d0;
          p = EXP2(beta);
        }
      }
    }
    float fv = (lane < Tn) ? beta + endv[lane] * LOG2E : -INFINITY;
    float m = fv;
    #pragma unroll
    for (int off = 32; off; off >>= 1) m = fmaxf(m, __shfl_xor(m, off));
    float e = (lane < Tn) ? EXP2(fv - m) : 0.f;
    #pragma unroll
    for (int off = 32; off; off >>= 1) e += __shfl_xor(e, off);
    if (lane == 0) wsLogZ[b] = (Zref + m + LOG2(e)) * LN2f;

  } else if (role == 1) {
    // ---------------- Viterbi value forward (no index) ----------------
    float trv[48];
    #pragma unroll
    for (int i = 0; i < 48; ++i) trv[i] = trans[i*Tn + j];
    float emq[8];
    #pragma unroll
    for (int d = 0; d < 8; ++d) {
      int s = 1 + d; s = s < len ? s : len - 1;
      emq[d] = fb[(size_t)s * Tn + j];
    }
    float v = startv[j] + fb[j];
    if (lane < Tn) vws[(size_t)b*Sn*Tn + lane] = v;
    for (int t = 1; t < len; t += 8) {
      #pragma unroll
      for (int i = 0; i < 48; ++i) PIN(trv[i]);  // in-loop: forces residency
      #pragma unroll
      for (int u = 0; u < 8; ++u) {
        const int tt = t + u;
        if (tt < len) {
          const float em_cur = emq[u];
          int tf = tt + 8; tf = tf < len ? tf : len - 1;
          emq[u] = fb[(size_t)tf * Tn + j];
          float q[48];
          #pragma unroll
          for (int i = 0; i < 48; ++i) q[i] = RL(v, i) + trv[i];
          float m16[16];
          #pragma unroll
          for (int uu = 0; uu < 16; ++uu)
            m16[uu] = fmaxf(fmaxf(q[3*uu], q[3*uu+1]), q[3*uu+2]);
          float m6a = fmaxf(fmaxf(m16[0],  m16[1]),  m16[2]);
          float m6b = fmaxf(fmaxf(m16[3],  m16[4]),  m16[5]);
          float m6c = fmaxf(fmaxf(m16[6],  m16[7]),  m16[8]);
          float m6d = fmaxf(fmaxf(m16[9],  m16[10]), m16[11]);
          float m6e = fmaxf(fmaxf(m16[12], m16[13]), m16[14]);
          const float best = fmaxf(fmaxf(fmaxf(m6a,m6b),m6c),
                                   fmaxf(fmaxf(m6d,m6e),m16[15]));
          v = best + em_cur;
          if (lane < Tn) vws[((size_t)b*Sn + tt)*Tn + lane] = v;
        }
      }
    }

  } else {
    // ---------------- gold score ----------------
    float g = 0.f;
    #pragma unroll
    for (int it = 0; it < Sn/64; ++it) {
      const int sg = it*64 + lane;
      if (sg < len) {
        const int la = labels[(size_t)b*Sn + sg];
        float e = fb[(size_t)sg*Tn + la];
        if (sg > 0) e += trans[labels[(size_t)b*Sn + sg - 1]*Tn + la];
        g += e;
      }
    }
    #pragma unroll
    for (int off = 32; off; off >>= 1) g += __shfl_xor(g, off);
    if (lane == 0) {
      g += startv[labels[(size_t)b*Sn]] + endv[labels[(size_t)b*Sn + len - 1]];
      wsGold[b] = g;
    }
  }
}

// ======================= bp_kernel: parallel backpointers =======================
__global__ __launch_bounds__(256) void bp_kernel(
    const float* __restrict__ vws,
    const int* __restrict__ mask,
    const float* __restrict__ trans,
    unsigned char* __restrict__ bpw)
{
  const int b    = blockIdx.x >> 3;
  const int oct  = blockIdx.x & 7;
  const int wv   = threadIdx.x >> 6;
  const int lane = threadIdx.x & 63;
  const int len = seq_len(mask, b, lane);
  const int j = (lane < Tn) ? lane : (Tn - 1);

  float trv[48];
  #pragma unroll
  for (int i = 0; i < 48; ++i) trv[i] = trans[i*Tn + j];

  const int t0 = oct*64 + wv*16;
  for (int i = 0; i < 16; ++i) {
    #pragma unroll
    for (int ii = 0; ii < 48; ++ii) PIN(trv[ii]);   // in-loop residency
    const int t = t0 + i;
    int te = t; te = te < 1 ? 1 : te; te = te < len ? te : len - 1;
    const float4* vp = reinterpret_cast<const float4*>(vws + ((size_t)b*Sn + te - 1)*Tn);
    float q[48];
    #pragma unroll
    for (int k = 0; k < 12; ++k) {
      const float4 a = vp[k];
      q[4*k+0] = a.x + trv[4*k+0];
      q[4*k+1] = a.y + trv[4*k+1];
      q[4*k+2] = a.z + trv[4*k+2];
      q[4*k+3] = a.w + trv[4*k+3];
    }
    float m16[16];
    #pragma unroll
    for (int u = 0; u < 16; ++u)
      m16[u] = fmaxf(fmaxf(q[3*u], q[3*u+1]), q[3*u+2]);
    float m6a = fmaxf(fmaxf(m16[0],  m16[1]),  m16[2]);
    float m6b = fmaxf(fmaxf(m16[3],  m16[4]),  m16[5]);
    float m6c = fmaxf(fmaxf(m16[6],  m16[7]),  m16[8]);
    float m6d = fmaxf(fmaxf(m16[9],  m16[10]), m16[11]);
    float m6e = fmaxf(fmaxf(m16[12], m16[13]), m16[14]);
    const float best = fmaxf(fmaxf(fmaxf(m6a,m6b),m6c),
                             fmaxf(fmaxf(m6d,m6e),m16[15]));
    unsigned s16[16];
    #pragma unroll
    for (int u = 0; u < 16; ++u) {
      const unsigned ka = __float_as_uint(q[3*u]   - best) | (unsigned)(3*u);
      const unsigned kb = __float_as_uint(q[3*u+1] - best) | (unsigned)(3*u+1);
      const unsigned kc = __float_as_uint(q[3*u+2] - best) | (unsigned)(3*u+2);
      s16[u] = umin2(umin2(ka, kb), kc);
    }
    unsigned i6a = umin2(umin2(s16[0],  s16[1]),  s16[2]);
    unsigned i6b = umin2(umin2(s16[3],  s16[4]),  s16[5]);
    unsigned i6c = umin2(umin2(s16[6],  s16[7]),  s16[8]);
    unsigned i6d = umin2(umin2(s16[9],  s16[10]), s16[11]);
    unsigned i6e = umin2(umin2(s16[12], s16[13]), s16[14]);
    const unsigned bidx = umin2(umin2(umin2(i6a,i6b),i6c), umin2(umin2(i6d,i6e),s16[15]));
    if (t >= 1 && t < len && lane < Tn)
      bpw[((size_t)b*Sn + t)*Tn + lane] = (unsigned char)bidx;
  }
}

// ======================= backtrace kernel =======================
__device__ __forceinline__ unsigned idw(int a) {
  return (unsigned)a | ((unsigned)(a+1)<<8) | ((unsigned)(a+2)<<16) | ((unsigned)(a+3)<<24);
}

__global__ __launch_bounds__(64, 1) void backtrace_kernel(
    const float* __restrict__ vws,
    const unsigned char* __restrict__ bpw,
    const int* __restrict__ mask,
    const float* __restrict__ endv,
    float* __restrict__ pred_out)
{
  __shared__ unsigned char bpL[Sn * Tn];     // 24 KB, stride 48
  __shared__ unsigned char pathL[384 * 64];  // 24 KB
  __shared__ int EA[8];

  const int b    = blockIdx.x;
  const int lane = threadIdx.x;
  const int len = seq_len(mask, b, lane);

  {
    const uint4* gb = reinterpret_cast<const uint4*>(bpw + (size_t)b*Sn*Tn);
    uint4* bl = reinterpret_cast<uint4*>(bpL);
    for (int i4 = lane; i4 < Sn*Tn/16; i4 += 64) {
      const int byte0 = i4*16;
      const int t = byte0 / Tn;
      const int j0 = byte0 - t*Tn;
      uint4 val;
      if (t >= 1 && t < len) val = gb[i4];
      else { val.x = idw(j0); val.y = idw(j0+4); val.z = idw(j0+8); val.w = idw(j0+12); }
      bl[i4] = val;
    }
  }

  float fv = (lane < Tn) ? vws[((size_t)b*Sn + len - 1)*Tn + lane] + endv[lane] : -INFINITY;
  int fi = (lane < Tn) ? lane : 64;
  #pragma unroll
  for (int off = 32; off; off >>= 1) {
    const float ov = __shfl_xor(fv, off);
    const int   oi = __shfl_xor(fi, off);
    if (ov > fv || (ov == fv && oi < fi)) { fv = ov; fi = oi; }
  }
  __syncthreads();

  #define JOB(r) \
    const int id##r  = lane + 64*(r); \
    const int seg##r = id##r & 7;     \
    int cur##r = id##r >> 3;          \
    const int bpb##r = seg##r * 64 * Tn; \
    const int pb##r  = id##r << 6;    \
    pathL[pb##r + 63] = (unsigned char)cur##r;
  JOB(0) JOB(1) JOB(2) JOB(3) JOB(4) JOB(5)
  for (int d = 62; d >= 0; --d) {
    const int o = (d + 1) * Tn;
    cur0 = bpL[bpb0 + o + cur0]; pathL[pb0 + d] = (unsigned char)cur0;
    cur1 = bpL[bpb1 + o + cur1]; pathL[pb1 + d] = (unsigned char)cur1;
    cur2 = bpL[bpb2 + o + cur2]; pathL[pb2 + d] = (unsigned char)cur2;
    cur3 = bpL[bpb3 + o + cur3]; pathL[pb3 + d] = (unsigned char)cur3;
    cur4 = bpL[bpb4 + o + cur4]; pathL[pb4 + d] = (unsigned char)cur4;
    cur5 = bpL[bpb5 + o + cur5]; pathL[pb5 + d] = (unsigned char)cur5;
  }
  #undef JOB
  __syncthreads();
  if (lane == 0) {
    int Ecur = fi;
    EA[7] = Ecur;
    for (int s = 7; s >= 1; --s) {
      const int bottom = pathL[((Ecur << 3) + s) * 64];
      Ecur = bpL[(s * 64) * Tn + bottom];
      EA[s-1] = Ecur;
    }
  }
  __syncthreads();
  #pragma unroll
  for (int r8 = 0; r8 < 8; ++r8) {
    const int t = r8*64 + lane;
    const int pv = pathL[((EA[r8] << 3) + r8) * 64 + lane];
    pred_out[(size_t)b*Sn + t] = (t < len) ? (float)pv : 0.f;
  }
}

__global__ void loss_reduce(const float* __restrict__ wsLogZ,
                            const float* __restrict__ wsGold,
                            float* __restrict__ out)
{
  const int lane = threadIdx.x;
  float v = wsLogZ[lane] - wsGold[lane];
  #pragma unroll
  for (int off = 32; off; off >>= 1) v += __shfl_xor(v, off);
  if (lane == 0) out[0] = v;
}

extern "C" void kernel_launch(void* const* d_in, const int* in_sizes, int n_in,
                              void* d_out, int out_size, void* d_ws, size_t ws_size,
                              hipStream_t stream) {
  const float* x      = (const float*)d_in[0];
  const int*   mask   = (const int*)  d_in[1];
  const int*   labels = (const int*)  d_in[2];
  const float* W      = (const float*)d_in[3];
  const float* bias   = (const float*)d_in[4];
  const float* trans  = (const float*)d_in[5];
  const float* startv = (const float*)d_in[6];
  const float* endv   = (const float*)d_in[7];

  float* out  = (float*)d_out;
  float* feat = out;
  float* pred = out + PRED_OFF;
  float* loss = out + LOSS_OFF;
  float* wsLogZ = (float*)d_ws;
  float* wsGold = wsLogZ + 64;
  float* vws = (float*)((char*)d_ws + VWS_BYTE_OFF);
  unsigned char* bpw = (unsigned char*)d_ws + BPW_BYTE_OFF;

  gemm_feat<<<(Bn*Sn)/128, 256, 0, stream>>>(x, W, bias, feat);
  crf_scan<<<192, 64, 0, stream>>>(feat, mask, labels, trans, startv, endv, vws, wsLogZ, wsGold);
  bp_kernel<<<512, 256, 0, stream>>>(vws, mask, trans, bpw);
  backtrace_kernel<<<64, 64, 0, stream>>>(vws, bpw, mask, endv, pred);
  loss_reduce<<<1, 64, 0, stream>>>(wsLogZ, wsGold, loss);
}

// Round 11
// 398.633 us; speedup vs baseline: 1.0110x; 1.0110x over previous
//
#include <hip/hip_runtime.h>
#include <hip/hip_bf16.h>
#include <math.h>

#define Bn 64
#define Sn 512
#define Hn 1024
#define Tn 48

#define LOG2E 1.4426950408889634f
#define LN2f  0.6931471805599453f

#define PRED_OFF (Bn*Sn*Tn)
#define LOSS_OFF (PRED_OFF + Bn*Sn)

#define RL(x,i) __int_as_float(__builtin_amdgcn_readlane(__float_as_int(x),(i)))

#if __has_builtin(__builtin_amdgcn_exp2f)
#define EXP2(x) __builtin_amdgcn_exp2f(x)
#else
#define EXP2(x) exp2f(x)
#endif
#if __has_builtin(__builtin_amdgcn_logf)
#define LOG2(x) __builtin_amdgcn_logf(x)
#else
#define LOG2(x) log2f(x)
#endif

__device__ __forceinline__ unsigned umin2(unsigned a, unsigned b) { return a < b ? a : b; }

// workspace layout (bytes): [0,256) logZ, [256,512) gold, [512, +6291456) v-values,
// then 1572864 bytes of backpointers.
#define VWS_BYTE_OFF 512
#define BPW_BYTE_OFF (512 + (size_t)Bn*Sn*Tn*4)

// ======================= GEMM: feat = x @ W + b =======================
#define DOT4(ACC,A,B) { ACC = fmaf((A).x,(B).x,ACC); ACC = fmaf((A).y,(B).y,ACC); ACC = fmaf((A).z,(B).z,ACC); ACC = fmaf((A).w,(B).w,ACC); }

__global__ __launch_bounds__(256) void gemm_feat(
    const float* __restrict__ x, const float* __restrict__ W,
    const float* __restrict__ bias, float* __restrict__ feat)
{
  __shared__ __align__(16) float xs[128][68];
  __shared__ __align__(16) float wsT[Tn][68];
  const int tid = threadIdx.x;
  const int srow  = tid >> 1;
  const int shalf = tid & 1;
  const int ty = tid >> 3;           // 0..31 -> rows ty, ty+32, ty+64, ty+96
  const int tx = tid & 7;            // 0..7  -> cols tx*6 .. tx*6+5
  const size_t row0 = (size_t)blockIdx.x * 128;

  float4 xreg[8];
  float  wreg[12];
  #pragma unroll
  for (int p = 0; p < 8; ++p)
    xreg[p] = *reinterpret_cast<const float4*>(&x[(row0 + srow)*Hn + shalf*32 + p*4]);
  #pragma unroll
  for (int i = 0; i < 12; ++i) {
    const int id = tid + i*256; const int kk = id/Tn; const int t = id - kk*Tn;
    wreg[i] = W[(size_t)kk*Tn + t];
  }

  float acc[4][6];
  #pragma unroll
  for (int r = 0; r < 4; ++r)
    #pragma unroll
    for (int c = 0; c < 6; ++c) acc[r][c] = 0.f;

  for (int k0 = 0; k0 < Hn; k0 += 64) {
    #pragma unroll
    for (int p = 0; p < 8; ++p)
      *reinterpret_cast<float4*>(&xs[srow][shalf*32 + p*4]) = xreg[p];
    #pragma unroll
    for (int i = 0; i < 12; ++i) {
      const int id = tid + i*256; const int kk = id/Tn; const int t = id - kk*Tn;
      wsT[t][kk] = wreg[i];
    }
    __syncthreads();
    if (k0 + 64 < Hn) {
      #pragma unroll
      for (int p = 0; p < 8; ++p)
        xreg[p] = *reinterpret_cast<const float4*>(&x[(row0 + srow)*Hn + (k0+64) + shalf*32 + p*4]);
      #pragma unroll
      for (int i = 0; i < 12; ++i) {
        const int id = tid + i*256; const int kk = id/Tn; const int t = id - kk*Tn;
        wreg[i] = W[(size_t)(k0 + 64 + kk)*Tn + t];
      }
    }
    #pragma unroll 4
    for (int kk = 0; kk < 64; kk += 4) {
      const float4 a0 = *reinterpret_cast<const float4*>(&xs[ty +  0][kk]);
      const float4 a1 = *reinterpret_cast<const float4*>(&xs[ty + 32][kk]);
      const float4 a2 = *reinterpret_cast<const float4*>(&xs[ty + 64][kk]);
      const float4 a3 = *reinterpret_cast<const float4*>(&xs[ty + 96][kk]);
      const float4 w0 = *reinterpret_cast<const float4*>(&wsT[tx*6+0][kk]);
      const float4 w1 = *reinterpret_cast<const float4*>(&wsT[tx*6+1][kk]);
      const float4 w2 = *reinterpret_cast<const float4*>(&wsT[tx*6+2][kk]);
      const float4 w3 = *reinterpret_cast<const float4*>(&wsT[tx*6+3][kk]);
      const float4 w4 = *reinterpret_cast<const float4*>(&wsT[tx*6+4][kk]);
      const float4 w5 = *reinterpret_cast<const float4*>(&wsT[tx*6+5][kk]);
      DOT4(acc[0][0],a0,w0) DOT4(acc[0][1],a0,w1) DOT4(acc[0][2],a0,w2)
      DOT4(acc[0][3],a0,w3) DOT4(acc[0][4],a0,w4) DOT4(acc[0][5],a0,w5)
      DOT4(acc[1][0],a1,w0) DOT4(acc[1][1],a1,w1) DOT4(acc[1][2],a1,w2)
      DOT4(acc[1][3],a1,w3) DOT4(acc[1][4],a1,w4) DOT4(acc[1][5],a1,w5)
      DOT4(acc[2][0],a2,w0) DOT4(acc[2][1],a2,w1) DOT4(acc[2][2],a2,w2)
      DOT4(acc[2][3],a2,w3) DOT4(acc[2][4],a2,w4) DOT4(acc[2][5],a2,w5)
      DOT4(acc[3][0],a3,w0) DOT4(acc[3][1],a3,w1) DOT4(acc[3][2],a3,w2)
      DOT4(acc[3][3],a3,w3) DOT4(acc[3][4],a3,w4) DOT4(acc[3][5],a3,w5)
    }
    __syncthreads();
  }
  #pragma unroll
  for (int c = 0; c < 6; ++c) {
    const int col = tx*6 + c;
    const float bv = bias[col];
    #pragma unroll
    for (int r = 0; r < 4; ++r)
      feat[(row0 + ty + r*32)*Tn + col] = acc[r][c] + bv;
  }
}

// ============ helper: sequence length (prefix mask) per wave ============
__device__ __forceinline__ int seq_len(const int* __restrict__ mask, int b, int lane) {
  int lc = 0;
  #pragma unroll
  for (int it = 0; it < Sn/64; ++it) lc += (mask[(size_t)b*Sn + it*64 + lane] != 0);
  #pragma unroll
  for (int off = 32; off; off >>= 1) lc += __shfl_xor(lc, off);
  return lc;
}

// ======================= crf_scan: 192 single-wave blocks =======================
// NO local arrays in hot paths: tables live in named float4s (cannot be scratched).
__global__ __launch_bounds__(64, 1) void crf_scan(
    const float* __restrict__ feat,
    const int* __restrict__ mask,
    const int* __restrict__ labels,
    const float* __restrict__ trans,
    const float* __restrict__ startv,
    const float* __restrict__ endv,
    float* __restrict__ vws,
    float* __restrict__ wsLogZ,
    float* __restrict__ wsGold)
{
  const int role = blockIdx.x >> 6;
  const int b    = blockIdx.x & 63;
  const int lane = threadIdx.x;
  const float* fb = feat + (size_t)b * Sn * Tn;
  const int len = seq_len(mask, b, lane);
  const int j = (lane < Tn) ? lane : (Tn - 1);

  if (role == 0) {
    // ---------------- log-partition ----------------
    float4 E0,E1,E2,E3,E4,E5,E6,E7,E8,E9,E10,E11;
    #define LDE(k) E##k.x = EXP2(trans[(4*k+0)*Tn + j]*LOG2E); \
                   E##k.y = EXP2(trans[(4*k+1)*Tn + j]*LOG2E); \
                   E##k.z = EXP2(trans[(4*k+2)*Tn + j]*LOG2E); \
                   E##k.w = EXP2(trans[(4*k+3)*Tn + j]*LOG2E);
    LDE(0) LDE(1) LDE(2) LDE(3) LDE(4) LDE(5) LDE(6) LDE(7) LDE(8) LDE(9) LDE(10) LDE(11)
    #undef LDE
    float emq0,emq1,emq2,emq3,emq4,emq5,emq6,emq7;
    #define LDEM(u) { int s = 1 + u; s = s < len ? s : len - 1; emq##u = fb[(size_t)s*Tn + j]; }
    LDEM(0) LDEM(1) LDEM(2) LDEM(3) LDEM(4) LDEM(5) LDEM(6) LDEM(7)
    #undef LDEM
    const float a0 = (startv[j] + fb[j]) * LOG2E;
    float Zref = RL(a0, 0);
    float beta = a0 - Zref;
    float p = EXP2(beta);
    #define FMAG(k) \
      s0 = fmaf(RL(p,4*k+0), E##k.x, s0); \
      s1 = fmaf(RL(p,4*k+1), E##k.y, s1); \
      s2 = fmaf(RL(p,4*k+2), E##k.z, s2); \
      s3 = fmaf(RL(p,4*k+3), E##k.w, s3);
    #define PSTEP(u) { const int tt = t + u; if (tt < len) { \
      const float em2 = emq##u * LOG2E; \
      int tf = tt + 8; tf = tf < len ? tf : len - 1; \
      emq##u = fb[(size_t)tf * Tn + j]; \
      float s0=0.f,s1=0.f,s2=0.f,s3=0.f; \
      FMAG(0) FMAG(1) FMAG(2) FMAG(3) FMAG(4) FMAG(5) \
      FMAG(6) FMAG(7) FMAG(8) FMAG(9) FMAG(10) FMAG(11) \
      const float dj = LOG2((s0+s1)+(s2+s3)) + em2; \
      const float d0 = RL(dj,0); \
      Zref += d0; beta = dj - d0; p = EXP2(beta); } }
    for (int t = 1; t < len; t += 8) {
      PSTEP(0) PSTEP(1) PSTEP(2) PSTEP(3) PSTEP(4) PSTEP(5) PSTEP(6) PSTEP(7)
    }
    #undef PSTEP
    #undef FMAG
    float fv = (lane < Tn) ? beta + endv[lane] * LOG2E : -INFINITY;
    float m = fv;
    #pragma unroll
    for (int off = 32; off; off >>= 1) m = fmaxf(m, __shfl_xor(m, off));
    float e = (lane < Tn) ? EXP2(fv - m) : 0.f;
    #pragma unroll
    for (int off = 32; off; off >>= 1) e += __shfl_xor(e, off);
    if (lane == 0) wsLogZ[b] = (Zref + m + LOG2(e)) * LN2f;

  } else if (role == 1) {
    // ---------------- Viterbi value forward (no index) ----------------
    float4 T0,T1,T2,T3,T4,T5,T6,T7,T8,T9,T10,T11;
    #define LDT(k) T##k.x = trans[(4*k+0)*Tn + j]; \
                   T##k.y = trans[(4*k+1)*Tn + j]; \
                   T##k.z = trans[(4*k+2)*Tn + j]; \
                   T##k.w = trans[(4*k+3)*Tn + j];
    LDT(0) LDT(1) LDT(2) LDT(3) LDT(4) LDT(5) LDT(6) LDT(7) LDT(8) LDT(9) LDT(10) LDT(11)
    #undef LDT
    float emq0,emq1,emq2,emq3,emq4,emq5,emq6,emq7;
    #define LDEM(u) { int s = 1 + u; s = s < len ? s : len - 1; emq##u = fb[(size_t)s*Tn + j]; }
    LDEM(0) LDEM(1) LDEM(2) LDEM(3) LDEM(4) LDEM(5) LDEM(6) LDEM(7)
    #undef LDEM
    float v = startv[j] + fb[j];
    if (lane < Tn) vws[(size_t)b*Sn*Tn + lane] = v;
    #define MAXG(k) const float g##k = fmaxf( \
      fmaxf(RL(v,4*k+0)+T##k.x, RL(v,4*k+1)+T##k.y), \
      fmaxf(RL(v,4*k+2)+T##k.z, RL(v,4*k+3)+T##k.w));
    #define VSTEP(u) { const int tt = t + u; if (tt < len) { \
      const float em_cur = emq##u; \
      int tf = tt + 8; tf = tf < len ? tf : len - 1; \
      emq##u = fb[(size_t)tf * Tn + j]; \
      MAXG(0) MAXG(1) MAXG(2) MAXG(3) MAXG(4) MAXG(5) \
      MAXG(6) MAXG(7) MAXG(8) MAXG(9) MAXG(10) MAXG(11) \
      const float h0 = fmaxf(fmaxf(g0,g1),fmaxf(g2,g3)); \
      const float h1 = fmaxf(fmaxf(g4,g5),fmaxf(g6,g7)); \
      const float h2 = fmaxf(fmaxf(g8,g9),fmaxf(g10,g11)); \
      const float best = fmaxf(fmaxf(h0,h1),h2); \
      v = best + em_cur; \
      if (lane < Tn) vws[((size_t)b*Sn + tt)*Tn + lane] = v; } }
    for (int t = 1; t < len; t += 8) {
      VSTEP(0) VSTEP(1) VSTEP(2) VSTEP(3) VSTEP(4) VSTEP(5) VSTEP(6) VSTEP(7)
    }
    #undef VSTEP
    #undef MAXG

  } else {
    // ---------------- gold score ----------------
    float g = 0.f;
    #pragma unroll
    for (int it = 0; it < Sn/64; ++it) {
      const int sg = it*64 + lane;
      if (sg < len) {
        const int la = labels[(size_t)b*Sn + sg];
        float e = fb[(size_t)sg*Tn + la];
        if (sg > 0) e += trans[labels[(size_t)b*Sn + sg - 1]*Tn + la];
        g += e;
      }
    }
    #pragma unroll
    for (int off = 32; off; off >>= 1) g += __shfl_xor(g, off);
    if (lane == 0) {
      g += startv[labels[(size_t)b*Sn]] + endv[labels[(size_t)b*Sn + len - 1]];
      wsGold[b] = g;
    }
  }
}

// ======================= bp_kernel: parallel backpointers =======================
// grid 512 blocks x 256 thr; block (b, oct): 4 waves x 16 t each. No local arrays.
__global__ __launch_bounds__(256) void bp_kernel(
    const float* __restrict__ vws,
    const int* __restrict__ mask,
    const float* __restrict__ trans,
    unsigned char* __restrict__ bpw)
{
  const int b    = blockIdx.x >> 3;
  const int oct  = blockIdx.x & 7;
  const int wv   = threadIdx.x >> 6;
  const int lane = threadIdx.x & 63;
  const int len = seq_len(mask, b, lane);
  const int j = (lane < Tn) ? lane : (Tn - 1);

  float4 T0,T1,T2,T3,T4,T5,T6,T7,T8,T9,T10,T11;
  #define LDT(k) T##k.x = trans[(4*k+0)*Tn + j]; \
                 T##k.y = trans[(4*k+1)*Tn + j]; \
                 T##k.z = trans[(4*k+2)*Tn + j]; \
                 T##k.w = trans[(4*k+3)*Tn + j];
  LDT(0) LDT(1) LDT(2) LDT(3) LDT(4) LDT(5) LDT(6) LDT(7) LDT(8) LDT(9) LDT(10) LDT(11)
  #undef LDT

  const int t0 = oct*64 + wv*16;
  for (int i = 0; i < 16; ++i) {
    const int t = t0 + i;
    int te = t; te = te < 1 ? 1 : te; te = te < len ? te : len - 1;
    const float4* vp = reinterpret_cast<const float4*>(vws + ((size_t)b*Sn + te - 1)*Tn);
    #define LDA(k) const float4 A##k = vp[k];
    LDA(0) LDA(1) LDA(2) LDA(3) LDA(4) LDA(5) LDA(6) LDA(7) LDA(8) LDA(9) LDA(10) LDA(11)
    #undef LDA
    #define GMAX(k) const float gq##k = fmaxf( \
      fmaxf(A##k.x+T##k.x, A##k.y+T##k.y), fmaxf(A##k.z+T##k.z, A##k.w+T##k.w));
    GMAX(0) GMAX(1) GMAX(2) GMAX(3) GMAX(4) GMAX(5)
    GMAX(6) GMAX(7) GMAX(8) GMAX(9) GMAX(10) GMAX(11)
    #undef GMAX
    const float h0 = fmaxf(fmaxf(gq0,gq1),fmaxf(gq2,gq3));
    const float h1 = fmaxf(fmaxf(gq4,gq5),fmaxf(gq6,gq7));
    const float h2 = fmaxf(fmaxf(gq8,gq9),fmaxf(gq10,gq11));
    const float best = fmaxf(fmaxf(h0,h1),h2);
    #define KEYG(k) umin2( \
      umin2(__float_as_uint((A##k.x+T##k.x)-best)|(unsigned)(4*k+0), \
            __float_as_uint((A##k.y+T##k.y)-best)|(unsigned)(4*k+1)), \
      umin2(__float_as_uint((A##k.z+T##k.z)-best)|(unsigned)(4*k+2), \
            __float_as_uint((A##k.w+T##k.w)-best)|(unsigned)(4*k+3)))
    const unsigned kA = umin2(umin2(KEYG(0), KEYG(1)), umin2(KEYG(2), KEYG(3)));
    const unsigned kB = umin2(umin2(KEYG(4), KEYG(5)), umin2(KEYG(6), KEYG(7)));
    const unsigned kC = umin2(umin2(KEYG(8), KEYG(9)), umin2(KEYG(10), KEYG(11)));
    #undef KEYG
    const unsigned bidx = umin2(umin2(kA, kB), kC);
    if (t >= 1 && t < len && lane < Tn)
      bpw[((size_t)b*Sn + t)*Tn + lane] = (unsigned char)bidx;
  }
}

// ======================= backtrace kernel =======================
__device__ __forceinline__ unsigned idw(int a) {
  return (unsigned)a | ((unsigned)(a+1)<<8) | ((unsigned)(a+2)<<16) | ((unsigned)(a+3)<<24);
}

__global__ __launch_bounds__(64, 1) void backtrace_kernel(
    const float* __restrict__ vws,
    const unsigned char* __restrict__ bpw,
    const int* __restrict__ mask,
    const float* __restrict__ endv,
    float* __restrict__ pred_out)
{
  __shared__ unsigned char bpL[Sn * Tn];     // 24 KB, stride 48
  __shared__ unsigned char pathL[384 * 64];  // 24 KB
  __shared__ int EA[8];

  const int b    = blockIdx.x;
  const int lane = threadIdx.x;
  const int len = seq_len(mask, b, lane);

  {
    const uint4* gb = reinterpret_cast<const uint4*>(bpw + (size_t)b*Sn*Tn);
    uint4* bl = reinterpret_cast<uint4*>(bpL);
    for (int i4 = lane; i4 < Sn*Tn/16; i4 += 64) {
      const int byte0 = i4*16;
      const int t = byte0 / Tn;
      const int j0 = byte0 - t*Tn;
      uint4 val;
      if (t >= 1 && t < len) val = gb[i4];
      else { val.x = idw(j0); val.y = idw(j0+4); val.z = idw(j0+8); val.w = idw(j0+12); }
      bl[i4] = val;
    }
  }

  float fv = (lane < Tn) ? vws[((size_t)b*Sn + len - 1)*Tn + lane] + endv[lane] : -INFINITY;
  int fi = (lane < Tn) ? lane : 64;
  #pragma unroll
  for (int off = 32; off; off >>= 1) {
    const float ov = __shfl_xor(fv, off);
    const int   oi = __shfl_xor(fi, off);
    if (ov > fv || (ov == fv && oi < fi)) { fv = ov; fi = oi; }
  }
  __syncthreads();

  #define JOB(r) \
    const int id##r  = lane + 64*(r); \
    const int seg##r = id##r & 7;     \
    int cur##r = id##r >> 3;          \
    const int bpb##r = seg##r * 64 * Tn; \
    const int pb##r  = id##r << 6;    \
    pathL[pb##r + 63] = (unsigned char)cur##r;
  JOB(0) JOB(1) JOB(2) JOB(3) JOB(4) JOB(5)
  for (int d = 62; d >= 0; --d) {
    const int o = (d + 1) * Tn;
    cur0 = bpL[bpb0 + o + cur0]; pathL[pb0 + d] = (unsigned char)cur0;
    cur1 = bpL[bpb1 + o + cur1]; pathL[pb1 + d] = (unsigned char)cur1;
    cur2 = bpL[bpb2 + o + cur2]; pathL[pb2 + d] = (unsigned char)cur2;
    cur3 = bpL[bpb3 + o + cur3]; pathL[pb3 + d] = (unsigned char)cur3;
    cur4 = bpL[bpb4 + o + cur4]; pathL[pb4 + d] = (unsigned char)cur4;
    cur5 = bpL[bpb5 + o + cur5]; pathL[pb5 + d] = (unsigned char)cur5;
  }
  #undef JOB
  __syncthreads();
  if (lane == 0) {
    int Ecur = fi;
    EA[7] = Ecur;
    for (int s = 7; s >= 1; --s) {
      const int bottom = pathL[((Ecur << 3) + s) * 64];
      Ecur = bpL[(s * 64) * Tn + bottom];
      EA[s-1] = Ecur;
    }
  }
  __syncthreads();
  #pragma unroll
  for (int r8 = 0; r8 < 8; ++r8) {
    const int t = r8*64 + lane;
    const int pv = pathL[((EA[r8] << 3) + r8) * 64 + lane];
    pred_out[(size_t)b*Sn + t] = (t < len) ? (float)pv : 0.f;
  }
}

__global__ void loss_reduce(const float* __restrict__ wsLogZ,
                            const float* __restrict__ wsGold,
                            float* __restrict__ out)
{
  const int lane = threadIdx.x;
  float v = wsLogZ[lane] - wsGold[lane];
  #pragma unroll
  for (int off = 32; off; off >>= 1) v += __shfl_xor(v, off);
  if (lane == 0) out[0] = v;
}

extern "C" void kernel_launch(void* const* d_in, const int* in_sizes, int n_in,
                              void* d_out, int out_size, void* d_ws, size_t ws_size,
                              hipStream_t stream) {
  const float* x      = (const float*)d_in[0];
  const int*   mask   = (const int*)  d_in[1];
  const int*   labels = (const int*)  d_in[2];
  const float* W      = (const float*)d_in[3];
  const float* bias   = (const float*)d_in[4];
  const float* trans  = (const float*)d_in[5];
  const float* startv = (const float*)d_in[6];
  const float* endv   = (const float*)d_in[7];

  float* out  = (float*)d_out;
  float* feat = out;
  float* pred = out + PRED_OFF;
  float* loss = out + LOSS_OFF;
  float* wsLogZ = (float*)d_ws;
  float* wsGold = wsLogZ + 64;
  float* vws = (float*)((char*)d_ws + VWS_BYTE_OFF);
  unsigned char* bpw = (unsigned char*)d_ws + BPW_BYTE_OFF;

  gemm_feat<<<(Bn*Sn)/128, 256, 0, stream>>>(x, W, bias, feat);
  crf_scan<<<192, 64, 0, stream>>>(feat, mask, labels, trans, startv, endv, vws, wsLogZ, wsGold);
  bp_kernel<<<512, 256, 0, stream>>>(vws, mask, trans, bpw);
  backtrace_kernel<<<64, 64, 0, stream>>>(vws, bpw, mask, endv, pred);
  loss_reduce<<<1, 64, 0, stream>>>(wsLogZ, wsGold, loss);
}

// Round 12
// 343.137 us; speedup vs baseline: 1.1745x; 1.1617x over previous
//
#include <hip/hip_runtime.h>
#include <hip/hip_bf16.h>
#include <math.h>

#define Bn 64
#define Sn 512
#define Hn 1024
#define Tn 48

#define LOG2E 1.4426950408889634f
#define LN2f  0.6931471805599453f

#define PRED_OFF (Bn*Sn*Tn)
#define LOSS_OFF (PRED_OFF + Bn*Sn)

#define RL(x,i) __int_as_float(__builtin_amdgcn_readlane(__float_as_int(x),(i)))

#if __has_builtin(__builtin_amdgcn_exp2f)
#define EXP2(x) __builtin_amdgcn_exp2f(x)
#else
#define EXP2(x) exp2f(x)
#endif
#if __has_builtin(__builtin_amdgcn_logf)
#define LOG2(x) __builtin_amdgcn_logf(x)
#else
#define LOG2(x) log2f(x)
#endif

__device__ __forceinline__ unsigned umin2(unsigned a, unsigned b) { return a < b ? a : b; }

// workspace layout (bytes): [0,256) logZ, [256,512) gold, [512, +6291456) v-values,
// then 1572864 bytes of backpointers.
#define VWS_BYTE_OFF 512
#define BPW_BYTE_OFF (512 + (size_t)Bn*Sn*Tn*4)

// ======================= GEMM: feat = x @ W + b (R4 config, measured 88us) ===
#define DOT4(ACC,A,B) { ACC = fmaf((A).x,(B).x,ACC); ACC = fmaf((A).y,(B).y,ACC); ACC = fmaf((A).z,(B).z,ACC); ACC = fmaf((A).w,(B).w,ACC); }

__global__ __launch_bounds__(256) void gemm_feat(
    const float* __restrict__ x, const float* __restrict__ W,
    const float* __restrict__ bias, float* __restrict__ feat)
{
  __shared__ __align__(16) float xs[64][68];
  __shared__ __align__(16) float wsT[Tn][68];
  const int tid = threadIdx.x;
  const int srow = tid >> 2;
  const int sqc  = tid & 3;
  const int ty = tid >> 3;
  const int tx = tid & 7;
  const size_t row0 = (size_t)blockIdx.x * 64;

  float4 xreg[4];
  float  wreg[12];
  #pragma unroll
  for (int p = 0; p < 4; ++p)
    xreg[p] = *reinterpret_cast<const float4*>(&x[(row0 + srow)*Hn + (sqc + p*4)*4]);
  #pragma unroll
  for (int i = 0; i < 12; ++i) {
    const int id = tid + i*256; const int kk = id/Tn; const int t = id - kk*Tn;
    wreg[i] = W[(size_t)kk*Tn + t];
  }

  float acc[2][6];
  #pragma unroll
  for (int r = 0; r < 2; ++r)
    #pragma unroll
    for (int c = 0; c < 6; ++c) acc[r][c] = 0.f;

  for (int k0 = 0; k0 < Hn; k0 += 64) {
    #pragma unroll
    for (int p = 0; p < 4; ++p)
      *reinterpret_cast<float4*>(&xs[srow][(sqc + p*4)*4]) = xreg[p];
    #pragma unroll
    for (int i = 0; i < 12; ++i) {
      const int id = tid + i*256; const int kk = id/Tn; const int t = id - kk*Tn;
      wsT[t][kk] = wreg[i];
    }
    __syncthreads();
    if (k0 + 64 < Hn) {
      #pragma unroll
      for (int p = 0; p < 4; ++p)
        xreg[p] = *reinterpret_cast<const float4*>(&x[(row0 + srow)*Hn + (k0+64) + (sqc + p*4)*4]);
      #pragma unroll
      for (int i = 0; i < 12; ++i) {
        const int id = tid + i*256; const int kk = id/Tn; const int t = id - kk*Tn;
        wreg[i] = W[(size_t)(k0 + 64 + kk)*Tn + t];
      }
    }
    #pragma unroll 4
    for (int kk = 0; kk < 64; kk += 4) {
      const float4 a0 = *reinterpret_cast<const float4*>(&xs[ty*2+0][kk]);
      const float4 a1 = *reinterpret_cast<const float4*>(&xs[ty*2+1][kk]);
      const float4 w0 = *reinterpret_cast<const float4*>(&wsT[tx*6+0][kk]);
      const float4 w1 = *reinterpret_cast<const float4*>(&wsT[tx*6+1][kk]);
      const float4 w2 = *reinterpret_cast<const float4*>(&wsT[tx*6+2][kk]);
      const float4 w3 = *reinterpret_cast<const float4*>(&wsT[tx*6+3][kk]);
      const float4 w4 = *reinterpret_cast<const float4*>(&wsT[tx*6+4][kk]);
      const float4 w5 = *reinterpret_cast<const float4*>(&wsT[tx*6+5][kk]);
      DOT4(acc[0][0],a0,w0) DOT4(acc[0][1],a0,w1) DOT4(acc[0][2],a0,w2)
      DOT4(acc[0][3],a0,w3) DOT4(acc[0][4],a0,w4) DOT4(acc[0][5],a0,w5)
      DOT4(acc[1][0],a1,w0) DOT4(acc[1][1],a1,w1) DOT4(acc[1][2],a1,w2)
      DOT4(acc[1][3],a1,w3) DOT4(acc[1][4],a1,w4) DOT4(acc[1][5],a1,w5)
    }
    __syncthreads();
  }
  #pragma unroll
  for (int c = 0; c < 6; ++c) {
    const int col = tx*6 + c;
    const float bv = bias[col];
    #pragma unroll
    for (int r = 0; r < 2; ++r)
      feat[(row0 + ty*2 + r)*Tn + col] = acc[r][c] + bv;
  }
}

// ============ helper: sequence length (prefix mask) per wave ============
__device__ __forceinline__ int seq_len(const int* __restrict__ mask, int b, int lane) {
  int lc = 0;
  #pragma unroll
  for (int it = 0; it < Sn/64; ++it) lc += (mask[(size_t)b*Sn + it*64 + lane] != 0);
  #pragma unroll
  for (int off = 32; off; off >>= 1) lc += __shfl_xor(lc, off);
  return lc;
}

// ======================= crf_scan: 192 single-wave blocks =======================
// Tables live in LDS (same shared object as the state buffer -> cannot be
// rematerialized into per-step global loads). Per step: 12 broadcast b128
// state reads + 12 table-row b128 reads + VALU.
#define ETS 52   // Et row stride in floats (16B-aligned, ~6-way banked)

__global__ __launch_bounds__(64, 1) void crf_scan(
    const float* __restrict__ feat,
    const int* __restrict__ mask,
    const int* __restrict__ labels,
    const float* __restrict__ trans,
    const float* __restrict__ startv,
    const float* __restrict__ endv,
    float* __restrict__ vws,
    float* __restrict__ wsLogZ,
    float* __restrict__ wsGold)
{
  __shared__ __align__(16) float LB[64 + 48*ETS];  // [0..63]=state, rest=table

  const int role = blockIdx.x >> 6;
  const int b    = blockIdx.x & 63;
  const int lane = threadIdx.x;
  const float* fb = feat + (size_t)b * Sn * Tn;
  const int len = seq_len(mask, b, lane);
  const int j = (lane < Tn) ? lane : (Tn - 1);

  const float4* sv4 = reinterpret_cast<const float4*>(&LB[0]);
  const float4* et4 = reinterpret_cast<const float4*>(&LB[64 + j*ETS]);

  if (role == 0) {
    // ---------------- log-partition ----------------
    // table: LB[64 + j*ETS + i] = exp2(trans[i][j]*log2e)
    for (int idx = lane; idx < Tn*Tn; idx += 64) {
      const int ii = idx / Tn, jj = idx - (idx/Tn)*Tn;
      LB[64 + jj*ETS + ii] = EXP2(trans[idx] * LOG2E);
    }
    __syncthreads();
    float emq0,emq1,emq2,emq3,emq4,emq5,emq6,emq7;
    #define LDEM(u) { int s = 1 + u; s = s < len ? s : len - 1; emq##u = fb[(size_t)s*Tn + j]; }
    LDEM(0) LDEM(1) LDEM(2) LDEM(3) LDEM(4) LDEM(5) LDEM(6) LDEM(7)
    #undef LDEM
    const float a0 = (startv[j] + fb[j]) * LOG2E;
    float Zref = RL(a0, 0);
    float beta = a0 - Zref;
    LB[lane] = EXP2(beta);
    #define PSTEP(u) { const int tt = t + u; if (tt < len) { \
      const float em2 = emq##u * LOG2E; \
      int tf = tt + 8; tf = tf < len ? tf : len - 1; \
      emq##u = fb[(size_t)tf * Tn + j]; \
      float s0=0.f,s1=0.f,s2=0.f,s3=0.f; \
      _Pragma("unroll") \
      for (int r = 0; r < 12; ++r) { \
        const float4 pv = sv4[r]; \
        const float4 ev = et4[r]; \
        s0 = fmaf(pv.x, ev.x, s0); \
        s1 = fmaf(pv.y, ev.y, s1); \
        s2 = fmaf(pv.z, ev.z, s2); \
        s3 = fmaf(pv.w, ev.w, s3); \
      } \
      const float dj = LOG2((s0+s1)+(s2+s3)) + em2; \
      const float d0 = RL(dj,0); \
      Zref += d0; beta = dj - d0; \
      LB[lane] = EXP2(beta); } }
    for (int t = 1; t < len; t += 8) {
      PSTEP(0) PSTEP(1) PSTEP(2) PSTEP(3) PSTEP(4) PSTEP(5) PSTEP(6) PSTEP(7)
    }
    #undef PSTEP
    float fv = (lane < Tn) ? beta + endv[lane] * LOG2E : -INFINITY;
    float m = fv;
    #pragma unroll
    for (int off = 32; off; off >>= 1) m = fmaxf(m, __shfl_xor(m, off));
    float e = (lane < Tn) ? EXP2(fv - m) : 0.f;
    #pragma unroll
    for (int off = 32; off; off >>= 1) e += __shfl_xor(e, off);
    if (lane == 0) wsLogZ[b] = (Zref + m + LOG2(e)) * LN2f;

  } else if (role == 1) {
    // ---------------- Viterbi value forward (no index) ----------------
    // table: LB[64 + j*ETS + i] = trans[i][j]
    for (int idx = lane; idx < Tn*Tn; idx += 64) {
      const int ii = idx / Tn, jj = idx - (idx/Tn)*Tn;
      LB[64 + jj*ETS + ii] = trans[idx];
    }
    __syncthreads();
    float emq0,emq1,emq2,emq3,emq4,emq5,emq6,emq7;
    #define LDEM(u) { int s = 1 + u; s = s < len ? s : len - 1; emq##u = fb[(size_t)s*Tn + j]; }
    LDEM(0) LDEM(1) LDEM(2) LDEM(3) LDEM(4) LDEM(5) LDEM(6) LDEM(7)
    #undef LDEM
    float v = startv[j] + fb[j];
    LB[lane] = v;
    if (lane < Tn) vws[(size_t)b*Sn*Tn + lane] = v;
    #define VSTEP(u) { const int tt = t + u; if (tt < len) { \
      const float em_cur = emq##u; \
      int tf = tt + 8; tf = tf < len ? tf : len - 1; \
      emq##u = fb[(size_t)tf * Tn + j]; \
      float g0 = -INFINITY, g1 = -INFINITY, g2 = -INFINITY, g3 = -INFINITY; \
      _Pragma("unroll") \
      for (int r = 0; r < 12; ++r) { \
        const float4 pv = sv4[r]; \
        const float4 tv = et4[r]; \
        g0 = fmaxf(g0, pv.x + tv.x); \
        g1 = fmaxf(g1, pv.y + tv.y); \
        g2 = fmaxf(g2, pv.z + tv.z); \
        g3 = fmaxf(g3, pv.w + tv.w); \
      } \
      const float best = fmaxf(fmaxf(g0,g1), fmaxf(g2,g3)); \
      v = best + em_cur; \
      LB[lane] = v; \
      if (lane < Tn) vws[((size_t)b*Sn + tt)*Tn + lane] = v; } }
    for (int t = 1; t < len; t += 8) {
      VSTEP(0) VSTEP(1) VSTEP(2) VSTEP(3) VSTEP(4) VSTEP(5) VSTEP(6) VSTEP(7)
    }
    #undef VSTEP

  } else {
    // ---------------- gold score ----------------
    float g = 0.f;
    #pragma unroll
    for (int it = 0; it < Sn/64; ++it) {
      const int sg = it*64 + lane;
      if (sg < len) {
        const int la = labels[(size_t)b*Sn + sg];
        float e = fb[(size_t)sg*Tn + la];
        if (sg > 0) e += trans[labels[(size_t)b*Sn + sg - 1]*Tn + la];
        g += e;
      }
    }
    #pragma unroll
    for (int off = 32; off; off >>= 1) g += __shfl_xor(g, off);
    if (lane == 0) {
      g += startv[labels[(size_t)b*Sn]] + endv[labels[(size_t)b*Sn + len - 1]];
      wsGold[b] = g;
    }
  }
}

// ======================= bp_kernel: parallel backpointers =======================
// grid 512 blocks x 256 thr; block (b, oct): 4 waves x 16 t each. No local arrays.
__global__ __launch_bounds__(256) void bp_kernel(
    const float* __restrict__ vws,
    const int* __restrict__ mask,
    const float* __restrict__ trans,
    unsigned char* __restrict__ bpw)
{
  const int b    = blockIdx.x >> 3;
  const int oct  = blockIdx.x & 7;
  const int wv   = threadIdx.x >> 6;
  const int lane = threadIdx.x & 63;
  const int len = seq_len(mask, b, lane);
  const int j = (lane < Tn) ? lane : (Tn - 1);

  float4 T0,T1,T2,T3,T4,T5,T6,T7,T8,T9,T10,T11;
  #define LDT(k) T##k.x = trans[(4*k+0)*Tn + j]; \
                 T##k.y = trans[(4*k+1)*Tn + j]; \
                 T##k.z = trans[(4*k+2)*Tn + j]; \
                 T##k.w = trans[(4*k+3)*Tn + j];
  LDT(0) LDT(1) LDT(2) LDT(3) LDT(4) LDT(5) LDT(6) LDT(7) LDT(8) LDT(9) LDT(10) LDT(11)
  #undef LDT

  const int t0 = oct*64 + wv*16;
  for (int i = 0; i < 16; ++i) {
    const int t = t0 + i;
    int te = t; te = te < 1 ? 1 : te; te = te < len ? te : len - 1;
    const float4* vp = reinterpret_cast<const float4*>(vws + ((size_t)b*Sn + te - 1)*Tn);
    #define LDA(k) const float4 A##k = vp[k];
    LDA(0) LDA(1) LDA(2) LDA(3) LDA(4) LDA(5) LDA(6) LDA(7) LDA(8) LDA(9) LDA(10) LDA(11)
    #undef LDA
    #define GMAX(k) const float gq##k = fmaxf( \
      fmaxf(A##k.x+T##k.x, A##k.y+T##k.y), fmaxf(A##k.z+T##k.z, A##k.w+T##k.w));
    GMAX(0) GMAX(1) GMAX(2) GMAX(3) GMAX(4) GMAX(5)
    GMAX(6) GMAX(7) GMAX(8) GMAX(9) GMAX(10) GMAX(11)
    #undef GMAX
    const float h0 = fmaxf(fmaxf(gq0,gq1),fmaxf(gq2,gq3));
    const float h1 = fmaxf(fmaxf(gq4,gq5),fmaxf(gq6,gq7));
    const float h2 = fmaxf(fmaxf(gq8,gq9),fmaxf(gq10,gq11));
    const float best = fmaxf(fmaxf(h0,h1),h2);
    #define KEYG(k) umin2( \
      umin2(__float_as_uint((A##k.x+T##k.x)-best)|(unsigned)(4*k+0), \
            __float_as_uint((A##k.y+T##k.y)-best)|(unsigned)(4*k+1)), \
      umin2(__float_as_uint((A##k.z+T##k.z)-best)|(unsigned)(4*k+2), \
            __float_as_uint((A##k.w+T##k.w)-best)|(unsigned)(4*k+3)))
    const unsigned kA = umin2(umin2(KEYG(0), KEYG(1)), umin2(KEYG(2), KEYG(3)));
    const unsigned kB = umin2(umin2(KEYG(4), KEYG(5)), umin2(KEYG(6), KEYG(7)));
    const unsigned kC = umin2(umin2(KEYG(8), KEYG(9)), umin2(KEYG(10), KEYG(11)));
    #undef KEYG
    const unsigned bidx = umin2(umin2(kA, kB), kC);
    if (t >= 1 && t < len && lane < Tn)
      bpw[((size_t)b*Sn + t)*Tn + lane] = (unsigned char)bidx;
  }
}

// ======================= backtrace kernel =======================
__device__ __forceinline__ unsigned idw(int a) {
  return (unsigned)a | ((unsigned)(a+1)<<8) | ((unsigned)(a+2)<<16) | ((unsigned)(a+3)<<24);
}

__global__ __launch_bounds__(64, 1) void backtrace_kernel(
    const float* __restrict__ vws,
    const unsigned char* __restrict__ bpw,
    const int* __restrict__ mask,
    const float* __restrict__ endv,
    float* __restrict__ pred_out)
{
  __shared__ unsigned char bpL[Sn * Tn];     // 24 KB, stride 48
  __shared__ unsigned char pathL[384 * 64];  // 24 KB
  __shared__ int EA[8];

  const int b    = blockIdx.x;
  const int lane = threadIdx.x;
  const int len = seq_len(mask, b, lane);

  {
    const uint4* gb = reinterpret_cast<const uint4*>(bpw + (size_t)b*Sn*Tn);
    uint4* bl = reinterpret_cast<uint4*>(bpL);
    for (int i4 = lane; i4 < Sn*Tn/16; i4 += 64) {
      const int byte0 = i4*16;
      const int t = byte0 / Tn;
      const int j0 = byte0 - t*Tn;
      uint4 val;
      if (t >= 1 && t < len) val = gb[i4];
      else { val.x = idw(j0); val.y = idw(j0+4); val.z = idw(j0+8); val.w = idw(j0+12); }
      bl[i4] = val;
    }
  }

  float fv = (lane < Tn) ? vws[((size_t)b*Sn + len - 1)*Tn + lane] + endv[lane] : -INFINITY;
  int fi = (lane < Tn) ? lane : 64;
  #pragma unroll
  for (int off = 32; off; off >>= 1) {
    const float ov = __shfl_xor(fv, off);
    const int   oi = __shfl_xor(fi, off);
    if (ov > fv || (ov == fv && oi < fi)) { fv = ov; fi = oi; }
  }
  __syncthreads();

  #define JOB(r) \
    const int id##r  = lane + 64*(r); \
    const int seg##r = id##r & 7;     \
    int cur##r = id##r >> 3;          \
    const int bpb##r = seg##r * 64 * Tn; \
    const int pb##r  = id##r << 6;    \
    pathL[pb##r + 63] = (unsigned char)cur##r;
  JOB(0) JOB(1) JOB(2) JOB(3) JOB(4) JOB(5)
  for (int d = 62; d >= 0; --d) {
    const int o = (d + 1) * Tn;
    cur0 = bpL[bpb0 + o + cur0]; pathL[pb0 + d] = (unsigned char)cur0;
    cur1 = bpL[bpb1 + o + cur1]; pathL[pb1 + d] = (unsigned char)cur1;
    cur2 = bpL[bpb2 + o + cur2]; pathL[pb2 + d] = (unsigned char)cur2;
    cur3 = bpL[bpb3 + o + cur3]; pathL[pb3 + d] = (unsigned char)cur3;
    cur4 = bpL[bpb4 + o + cur4]; pathL[pb4 + d] = (unsigned char)cur4;
    cur5 = bpL[bpb5 + o + cur5]; pathL[pb5 + d] = (unsigned char)cur5;
  }
  #undef JOB
  __syncthreads();
  if (lane == 0) {
    int Ecur = fi;
    EA[7] = Ecur;
    for (int s = 7; s >= 1; --s) {
      const int bottom = pathL[((Ecur << 3) + s) * 64];
      Ecur = bpL[(s * 64) * Tn + bottom];
      EA[s-1] = Ecur;
    }
  }
  __syncthreads();
  #pragma unroll
  for (int r8 = 0; r8 < 8; ++r8) {
    const int t = r8*64 + lane;
    const int pv = pathL[((EA[r8] << 3) + r8) * 64 + lane];
    pred_out[(size_t)b*Sn + t] = (t < len) ? (float)pv : 0.f;
  }
}

__global__ void loss_reduce(const float* __restrict__ wsLogZ,
                            const float* __restrict__ wsGold,
                            float* __restrict__ out)
{
  const int lane = threadIdx.x;
  float v = wsLogZ[lane] - wsGold[lane];
  #pragma unroll
  for (int off = 32; off; off >>= 1) v += __shfl_xor(v, off);
  if (lane == 0) out[0] = v;
}

extern "C" void kernel_launch(void* const* d_in, const int* in_sizes, int n_in,
                              void* d_out, int out_size, void* d_ws, size_t ws_size,
                              hipStream_t stream) {
  const float* x      = (const float*)d_in[0];
  const int*   mask   = (const int*)  d_in[1];
  const int*   labels = (const int*)  d_in[2];
  const float* W      = (const float*)d_in[3];
  const float* bias   = (const float*)d_in[4];
  const float* trans  = (const float*)d_in[5];
  const float* startv = (const float*)d_in[6];
  const float* endv   = (const float*)d_in[7];

  float* out  = (float*)d_out;
  float* feat = out;
  float* pred = out + PRED_OFF;
  float* loss = out + LOSS_OFF;
  float* wsLogZ = (float*)d_ws;
  float* wsGold = wsLogZ + 64;
  float* vws = (float*)((char*)d_ws + VWS_BYTE_OFF);
  unsigned char* bpw = (unsigned char*)d_ws + BPW_BYTE_OFF;

  gemm_feat<<<(Bn*Sn)/64, 256, 0, stream>>>(x, W, bias, feat);
  crf_scan<<<192, 64, 0, stream>>>(feat, mask, labels, trans, startv, endv, vws, wsLogZ, wsGold);
  bp_kernel<<<512, 256, 0, stream>>>(vws, mask, trans, bpw);
  backtrace_kernel<<<64, 64, 0, stream>>>(vws, bpw, mask, endv, pred);
  loss_reduce<<<1, 64, 0, stream>>>(wsLogZ, wsGold, loss);
}

// Round 13
// 325.626 us; speedup vs baseline: 1.2376x; 1.0538x over previous
//
#include <hip/hip_runtime.h>
#include <hip/hip_bf16.h>
#include <math.h>

#define Bn 64
#define Sn 512
#define Hn 1024
#define Tn 48

#define LOG2E 1.4426950408889634f
#define LN2f  0.6931471805599453f

#define PRED_OFF (Bn*Sn*Tn)
#define LOSS_OFF (PRED_OFF + Bn*Sn)

#define RL(x,i) __int_as_float(__builtin_amdgcn_readlane(__float_as_int(x),(i)))

#if __has_builtin(__builtin_amdgcn_exp2f)
#define EXP2(x) __builtin_amdgcn_exp2f(x)
#else
#define EXP2(x) exp2f(x)
#endif
#if __has_builtin(__builtin_amdgcn_logf)
#define LOG2(x) __builtin_amdgcn_logf(x)
#else
#define LOG2(x) log2f(x)
#endif

__device__ __forceinline__ unsigned umin2(unsigned a, unsigned b) { return a < b ? a : b; }

// workspace layout (bytes): [0,256) logZ, [256,512) gold, [512, +6291456) v-values,
// then 1572864 bytes of backpointers.
#define VWS_BYTE_OFF 512
#define BPW_BYTE_OFF (512 + (size_t)Bn*Sn*Tn*4)

// ======================= GEMM: feat = x @ W + b (R4 config, measured 88us) ===
#define DOT4(ACC,A,B) { ACC = fmaf((A).x,(B).x,ACC); ACC = fmaf((A).y,(B).y,ACC); ACC = fmaf((A).z,(B).z,ACC); ACC = fmaf((A).w,(B).w,ACC); }

__global__ __launch_bounds__(256) void gemm_feat(
    const float* __restrict__ x, const float* __restrict__ W,
    const float* __restrict__ bias, float* __restrict__ feat)
{
  __shared__ __align__(16) float xs[64][68];
  __shared__ __align__(16) float wsT[Tn][68];
  const int tid = threadIdx.x;
  const int srow = tid >> 2;
  const int sqc  = tid & 3;
  const int ty = tid >> 3;
  const int tx = tid & 7;
  const size_t row0 = (size_t)blockIdx.x * 64;

  float4 xreg[4];
  float  wreg[12];
  #pragma unroll
  for (int p = 0; p < 4; ++p)
    xreg[p] = *reinterpret_cast<const float4*>(&x[(row0 + srow)*Hn + (sqc + p*4)*4]);
  #pragma unroll
  for (int i = 0; i < 12; ++i) {
    const int id = tid + i*256; const int kk = id/Tn; const int t = id - kk*Tn;
    wreg[i] = W[(size_t)kk*Tn + t];
  }

  float acc[2][6];
  #pragma unroll
  for (int r = 0; r < 2; ++r)
    #pragma unroll
    for (int c = 0; c < 6; ++c) acc[r][c] = 0.f;

  for (int k0 = 0; k0 < Hn; k0 += 64) {
    #pragma unroll
    for (int p = 0; p < 4; ++p)
      *reinterpret_cast<float4*>(&xs[srow][(sqc + p*4)*4]) = xreg[p];
    #pragma unroll
    for (int i = 0; i < 12; ++i) {
      const int id = tid + i*256; const int kk = id/Tn; const int t = id - kk*Tn;
      wsT[t][kk] = wreg[i];
    }
    __syncthreads();
    if (k0 + 64 < Hn) {
      #pragma unroll
      for (int p = 0; p < 4; ++p)
        xreg[p] = *reinterpret_cast<const float4*>(&x[(row0 + srow)*Hn + (k0+64) + (sqc + p*4)*4]);
      #pragma unroll
      for (int i = 0; i < 12; ++i) {
        const int id = tid + i*256; const int kk = id/Tn; const int t = id - kk*Tn;
        wreg[i] = W[(size_t)(k0 + 64 + kk)*Tn + t];
      }
    }
    #pragma unroll 4
    for (int kk = 0; kk < 64; kk += 4) {
      const float4 a0 = *reinterpret_cast<const float4*>(&xs[ty*2+0][kk]);
      const float4 a1 = *reinterpret_cast<const float4*>(&xs[ty*2+1][kk]);
      const float4 w0 = *reinterpret_cast<const float4*>(&wsT[tx*6+0][kk]);
      const float4 w1 = *reinterpret_cast<const float4*>(&wsT[tx*6+1][kk]);
      const float4 w2 = *reinterpret_cast<const float4*>(&wsT[tx*6+2][kk]);
      const float4 w3 = *reinterpret_cast<const float4*>(&wsT[tx*6+3][kk]);
      const float4 w4 = *reinterpret_cast<const float4*>(&wsT[tx*6+4][kk]);
      const float4 w5 = *reinterpret_cast<const float4*>(&wsT[tx*6+5][kk]);
      DOT4(acc[0][0],a0,w0) DOT4(acc[0][1],a0,w1) DOT4(acc[0][2],a0,w2)
      DOT4(acc[0][3],a0,w3) DOT4(acc[0][4],a0,w4) DOT4(acc[0][5],a0,w5)
      DOT4(acc[1][0],a1,w0) DOT4(acc[1][1],a1,w1) DOT4(acc[1][2],a1,w2)
      DOT4(acc[1][3],a1,w3) DOT4(acc[1][4],a1,w4) DOT4(acc[1][5],a1,w5)
    }
    __syncthreads();
  }
  #pragma unroll
  for (int c = 0; c < 6; ++c) {
    const int col = tx*6 + c;
    const float bv = bias[col];
    #pragma unroll
    for (int r = 0; r < 2; ++r)
      feat[(row0 + ty*2 + r)*Tn + col] = acc[r][c] + bv;
  }
}

// ============ helper: sequence length (prefix mask) per wave ============
__device__ __forceinline__ int seq_len(const int* __restrict__ mask, int b, int lane) {
  int lc = 0;
  #pragma unroll
  for (int it = 0; it < Sn/64; ++it) lc += (mask[(size_t)b*Sn + it*64 + lane] != 0);
  #pragma unroll
  for (int off = 32; off; off >>= 1) lc += __shfl_xor(lc, off);
  return lc;
}

// ======================= crf_scan: 192 single-wave blocks =======================
// Tables staged via LDS then loaded ONCE into named registers. The per-step
// LB[lane] ds_write (dynamic index, same shared object) makes the table loads
// non-rematerializable -> they stay resident in VGPRs.
#define ETS 52   // table row stride in floats (16B-aligned)

__global__ __launch_bounds__(64, 1) void crf_scan(
    const float* __restrict__ feat,
    const int* __restrict__ mask,
    const int* __restrict__ labels,
    const float* __restrict__ trans,
    const float* __restrict__ startv,
    const float* __restrict__ endv,
    float* __restrict__ vws,
    float* __restrict__ wsLogZ,
    float* __restrict__ wsGold)
{
  __shared__ __align__(16) float LB[64 + 48*ETS];  // [0..63]=state, rest=table

  const int role = blockIdx.x >> 6;
  const int b    = blockIdx.x & 63;
  const int lane = threadIdx.x;
  const float* fb = feat + (size_t)b * Sn * Tn;
  const int len = seq_len(mask, b, lane);
  const int j = (lane < Tn) ? lane : (Tn - 1);

  const float4* sv4 = reinterpret_cast<const float4*>(&LB[0]);
  const float4* et4 = reinterpret_cast<const float4*>(&LB[64 + j*ETS]);

  if (role == 0) {
    // ---------------- log-partition ----------------
    for (int idx = lane; idx < Tn*Tn; idx += 64) {
      const int ii = idx / Tn, jj = idx - (idx/Tn)*Tn;
      LB[64 + jj*ETS + ii] = EXP2(trans[idx] * LOG2E);
    }
    __syncthreads();
    // hoist table to registers (non-rematerializable past in-loop LB writes)
    #define LDET(k) const float4 ET##k = et4[k];
    LDET(0) LDET(1) LDET(2) LDET(3) LDET(4) LDET(5)
    LDET(6) LDET(7) LDET(8) LDET(9) LDET(10) LDET(11)
    #undef LDET
    float emq0,emq1,emq2,emq3,emq4,emq5,emq6,emq7;
    #define LDEM(u) { int s = 1 + u; s = s < len ? s : len - 1; emq##u = fb[(size_t)s*Tn + j]; }
    LDEM(0) LDEM(1) LDEM(2) LDEM(3) LDEM(4) LDEM(5) LDEM(6) LDEM(7)
    #undef LDEM
    const float a0 = (startv[j] + fb[j]) * LOG2E;
    float Zref = RL(a0, 0);
    float beta = a0 - Zref;
    LB[lane] = EXP2(beta);
    #define FMAG(k) { const float4 pv = sv4[k]; \
      s0 = fmaf(pv.x, ET##k.x, s0); \
      s1 = fmaf(pv.y, ET##k.y, s1); \
      s2 = fmaf(pv.z, ET##k.z, s2); \
      s3 = fmaf(pv.w, ET##k.w, s3); }
    #define PSTEP(u) { const int tt = t + u; if (tt < len) { \
      const float em2 = emq##u * LOG2E; \
      int tf = tt + 8; tf = tf < len ? tf : len - 1; \
      emq##u = fb[(size_t)tf * Tn + j]; \
      float s0=0.f,s1=0.f,s2=0.f,s3=0.f; \
      FMAG(0) FMAG(1) FMAG(2) FMAG(3) FMAG(4) FMAG(5) \
      FMAG(6) FMAG(7) FMAG(8) FMAG(9) FMAG(10) FMAG(11) \
      const float dj = LOG2((s0+s1)+(s2+s3)) + em2; \
      const float d0 = RL(dj,0); \
      Zref += d0; beta = dj - d0; \
      LB[lane] = EXP2(beta); } }
    for (int t = 1; t < len; t += 8) {
      PSTEP(0) PSTEP(1) PSTEP(2) PSTEP(3) PSTEP(4) PSTEP(5) PSTEP(6) PSTEP(7)
    }
    #undef PSTEP
    #undef FMAG
    float fv = (lane < Tn) ? beta + endv[lane] * LOG2E : -INFINITY;
    float m = fv;
    #pragma unroll
    for (int off = 32; off; off >>= 1) m = fmaxf(m, __shfl_xor(m, off));
    float e = (lane < Tn) ? EXP2(fv - m) : 0.f;
    #pragma unroll
    for (int off = 32; off; off >>= 1) e += __shfl_xor(e, off);
    if (lane == 0) wsLogZ[b] = (Zref + m + LOG2(e)) * LN2f;

  } else if (role == 1) {
    // ---------------- Viterbi value forward (no index) ----------------
    for (int idx = lane; idx < Tn*Tn; idx += 64) {
      const int ii = idx / Tn, jj = idx - (idx/Tn)*Tn;
      LB[64 + jj*ETS + ii] = trans[idx];
    }
    __syncthreads();
    #define LDET(k) const float4 ET##k = et4[k];
    LDET(0) LDET(1) LDET(2) LDET(3) LDET(4) LDET(5)
    LDET(6) LDET(7) LDET(8) LDET(9) LDET(10) LDET(11)
    #undef LDET
    float emq0,emq1,emq2,emq3,emq4,emq5,emq6,emq7;
    #define LDEM(u) { int s = 1 + u; s = s < len ? s : len - 1; emq##u = fb[(size_t)s*Tn + j]; }
    LDEM(0) LDEM(1) LDEM(2) LDEM(3) LDEM(4) LDEM(5) LDEM(6) LDEM(7)
    #undef LDEM
    float v = startv[j] + fb[j];
    LB[lane] = v;
    if (lane < Tn) vws[(size_t)b*Sn*Tn + lane] = v;
    #define MAXG(k) { const float4 pv = sv4[k]; \
      g0 = fmaxf(g0, pv.x + ET##k.x); \
      g1 = fmaxf(g1, pv.y + ET##k.y); \
      g2 = fmaxf(g2, pv.z + ET##k.z); \
      g3 = fmaxf(g3, pv.w + ET##k.w); }
    #define VSTEP(u) { const int tt = t + u; if (tt < len) { \
      const float em_cur = emq##u; \
      int tf = tt + 8; tf = tf < len ? tf : len - 1; \
      emq##u = fb[(size_t)tf * Tn + j]; \
      float g0 = -INFINITY, g1 = -INFINITY, g2 = -INFINITY, g3 = -INFINITY; \
      MAXG(0) MAXG(1) MAXG(2) MAXG(3) MAXG(4) MAXG(5) \
      MAXG(6) MAXG(7) MAXG(8) MAXG(9) MAXG(10) MAXG(11) \
      const float best = fmaxf(fmaxf(g0,g1), fmaxf(g2,g3)); \
      v = best + em_cur; \
      LB[lane] = v; \
      if (lane < Tn) vws[((size_t)b*Sn + tt)*Tn + lane] = v; } }
    for (int t = 1; t < len; t += 8) {
      VSTEP(0) VSTEP(1) VSTEP(2) VSTEP(3) VSTEP(4) VSTEP(5) VSTEP(6) VSTEP(7)
    }
    #undef VSTEP
    #undef MAXG

  } else {
    // ---------------- gold score ----------------
    float g = 0.f;
    #pragma unroll
    for (int it = 0; it < Sn/64; ++it) {
      const int sg = it*64 + lane;
      if (sg < len) {
        const int la = labels[(size_t)b*Sn + sg];
        float e = fb[(size_t)sg*Tn + la];
        if (sg > 0) e += trans[labels[(size_t)b*Sn + sg - 1]*Tn + la];
        g += e;
      }
    }
    #pragma unroll
    for (int off = 32; off; off >>= 1) g += __shfl_xor(g, off);
    if (lane == 0) {
      g += startv[labels[(size_t)b*Sn]] + endv[labels[(size_t)b*Sn + len - 1]];
      wsGold[b] = g;
    }
  }
}

// ======================= bp_kernel: parallel backpointers =======================
__global__ __launch_bounds__(256) void bp_kernel(
    const float* __restrict__ vws,
    const int* __restrict__ mask,
    const float* __restrict__ trans,
    unsigned char* __restrict__ bpw)
{
  const int b    = blockIdx.x >> 3;
  const int oct  = blockIdx.x & 7;
  const int wv   = threadIdx.x >> 6;
  const int lane = threadIdx.x & 63;
  const int len = seq_len(mask, b, lane);
  const int j = (lane < Tn) ? lane : (Tn - 1);

  float4 T0,T1,T2,T3,T4,T5,T6,T7,T8,T9,T10,T11;
  #define LDT(k) T##k.x = trans[(4*k+0)*Tn + j]; \
                 T##k.y = trans[(4*k+1)*Tn + j]; \
                 T##k.z = trans[(4*k+2)*Tn + j]; \
                 T##k.w = trans[(4*k+3)*Tn + j];
  LDT(0) LDT(1) LDT(2) LDT(3) LDT(4) LDT(5) LDT(6) LDT(7) LDT(8) LDT(9) LDT(10) LDT(11)
  #undef LDT

  const int t0 = oct*64 + wv*16;
  for (int i = 0; i < 16; ++i) {
    const int t = t0 + i;
    int te = t; te = te < 1 ? 1 : te; te = te < len ? te : len - 1;
    const float4* vp = reinterpret_cast<const float4*>(vws + ((size_t)b*Sn + te - 1)*Tn);
    #define LDA(k) const float4 A##k = vp[k];
    LDA(0) LDA(1) LDA(2) LDA(3) LDA(4) LDA(5) LDA(6) LDA(7) LDA(8) LDA(9) LDA(10) LDA(11)
    #undef LDA
    #define GMAX(k) const float gq##k = fmaxf( \
      fmaxf(A##k.x+T##k.x, A##k.y+T##k.y), fmaxf(A##k.z+T##k.z, A##k.w+T##k.w));
    GMAX(0) GMAX(1) GMAX(2) GMAX(3) GMAX(4) GMAX(5)
    GMAX(6) GMAX(7) GMAX(8) GMAX(9) GMAX(10) GMAX(11)
    #undef GMAX
    const float h0 = fmaxf(fmaxf(gq0,gq1),fmaxf(gq2,gq3));
    const float h1 = fmaxf(fmaxf(gq4,gq5),fmaxf(gq6,gq7));
    const float h2 = fmaxf(fmaxf(gq8,gq9),fmaxf(gq10,gq11));
    const float best = fmaxf(fmaxf(h0,h1),h2);
    #define KEYG(k) umin2( \
      umin2(__float_as_uint((A##k.x+T##k.x)-best)|(unsigned)(4*k+0), \
            __float_as_uint((A##k.y+T##k.y)-best)|(unsigned)(4*k+1)), \
      umin2(__float_as_uint((A##k.z+T##k.z)-best)|(unsigned)(4*k+2), \
            __float_as_uint((A##k.w+T##k.w)-best)|(unsigned)(4*k+3)))
    const unsigned kA = umin2(umin2(KEYG(0), KEYG(1)), umin2(KEYG(2), KEYG(3)));
    const unsigned kB = umin2(umin2(KEYG(4), KEYG(5)), umin2(KEYG(6), KEYG(7)));
    const unsigned kC = umin2(umin2(KEYG(8), KEYG(9)), umin2(KEYG(10), KEYG(11)));
    #undef KEYG
    const unsigned bidx = umin2(umin2(kA, kB), kC);
    if (t >= 1 && t < len && lane < Tn)
      bpw[((size_t)b*Sn + t)*Tn + lane] = (unsigned char)bidx;
  }
}

// ======================= backtrace kernel =======================
__device__ __forceinline__ unsigned idw(int a) {
  return (unsigned)a | ((unsigned)(a+1)<<8) | ((unsigned)(a+2)<<16) | ((unsigned)(a+3)<<24);
}

__global__ __launch_bounds__(64, 1) void backtrace_kernel(
    const float* __restrict__ vws,
    const unsigned char* __restrict__ bpw,
    const int* __restrict__ mask,
    const float* __restrict__ endv,
    float* __restrict__ pred_out)
{
  __shared__ unsigned char bpL[Sn * Tn];     // 24 KB, stride 48
  __shared__ unsigned char pathL[384 * 64];  // 24 KB
  __shared__ int EA[8];

  const int b    = blockIdx.x;
  const int lane = threadIdx.x;
  const int len = seq_len(mask, b, lane);

  {
    const uint4* gb = reinterpret_cast<const uint4*>(bpw + (size_t)b*Sn*Tn);
    uint4* bl = reinterpret_cast<uint4*>(bpL);
    for (int i4 = lane; i4 < Sn*Tn/16; i4 += 64) {
      const int byte0 = i4*16;
      const int t = byte0 / Tn;
      const int j0 = byte0 - t*Tn;
      uint4 val;
      if (t >= 1 && t < len) val = gb[i4];
      else { val.x = idw(j0); val.y = idw(j0+4); val.z = idw(j0+8); val.w = idw(j0+12); }
      bl[i4] = val;
    }
  }

  float fv = (lane < Tn) ? vws[((size_t)b*Sn + len - 1)*Tn + lane] + endv[lane] : -INFINITY;
  int fi = (lane < Tn) ? lane : 64;
  #pragma unroll
  for (int off = 32; off; off >>= 1) {
    const float ov = __shfl_xor(fv, off);
    const int   oi = __shfl_xor(fi, off);
    if (ov > fv || (ov == fv && oi < fi)) { fv = ov; fi = oi; }
  }
  __syncthreads();

  #define JOB(r) \
    const int id##r  = lane + 64*(r); \
    const int seg##r = id##r & 7;     \
    int cur##r = id##r >> 3;          \
    const int bpb##r = seg##r * 64 * Tn; \
    const int pb##r  = id##r << 6;    \
    pathL[pb##r + 63] = (unsigned char)cur##r;
  JOB(0) JOB(1) JOB(2) JOB(3) JOB(4) JOB(5)
  for (int d = 62; d >= 0; --d) {
    const int o = (d + 1) * Tn;
    cur0 = bpL[bpb0 + o + cur0]; pathL[pb0 + d] = (unsigned char)cur0;
    cur1 = bpL[bpb1 + o + cur1]; pathL[pb1 + d] = (unsigned char)cur1;
    cur2 = bpL[bpb2 + o + cur2]; pathL[pb2 + d] = (unsigned char)cur2;
    cur3 = bpL[bpb3 + o + cur3]; pathL[pb3 + d] = (unsigned char)cur3;
    cur4 = bpL[bpb4 + o + cur4]; pathL[pb4 + d] = (unsigned char)cur4;
    cur5 = bpL[bpb5 + o + cur5]; pathL[pb5 + d] = (unsigned char)cur5;
  }
  #undef JOB
  __syncthreads();
  if (lane == 0) {
    int Ecur = fi;
    EA[7] = Ecur;
    for (int s = 7; s >= 1; --s) {
      const int bottom = pathL[((Ecur << 3) + s) * 64];
      Ecur = bpL[(s * 64) * Tn + bottom];
      EA[s-1] = Ecur;
    }
  }
  __syncthreads();
  #pragma unroll
  for (int r8 = 0; r8 < 8; ++r8) {
    const int t = r8*64 + lane;
    const int pv = pathL[((EA[r8] << 3) + r8) * 64 + lane];
    pred_out[(size_t)b*Sn + t] = (t < len) ? (float)pv : 0.f;
  }
}

__global__ void loss_reduce(const float* __restrict__ wsLogZ,
                            const float* __restrict__ wsGold,
                            float* __restrict__ out)
{
  const int lane = threadIdx.x;
  float v = wsLogZ[lane] - wsGold[lane];
  #pragma unroll
  for (int off = 32; off; off >>= 1) v += __shfl_xor(v, off);
  if (lane == 0) out[0] = v;
}

extern "C" void kernel_launch(void* const* d_in, const int* in_sizes, int n_in,
                              void* d_out, int out_size, void* d_ws, size_t ws_size,
                              hipStream_t stream) {
  const float* x      = (const float*)d_in[0];
  const int*   mask   = (const int*)  d_in[1];
  const int*   labels = (const int*)  d_in[2];
  const float* W      = (const float*)d_in[3];
  const float* bias   = (const float*)d_in[4];
  const float* trans  = (const float*)d_in[5];
  const float* startv = (const float*)d_in[6];
  const float* endv   = (const float*)d_in[7];

  float* out  = (float*)d_out;
  float* feat = out;
  float* pred = out + PRED_OFF;
  float* loss = out + LOSS_OFF;
  float* wsLogZ = (float*)d_ws;
  float* wsGold = wsLogZ + 64;
  float* vws = (float*)((char*)d_ws + VWS_BYTE_OFF);
  unsigned char* bpw = (unsigned char*)d_ws + BPW_BYTE_OFF;

  gemm_feat<<<(Bn*Sn)/64, 256, 0, stream>>>(x, W, bias, feat);
  crf_scan<<<192, 64, 0, stream>>>(feat, mask, labels, trans, startv, endv, vws, wsLogZ, wsGold);
  bp_kernel<<<512, 256, 0, stream>>>(vws, mask, trans, bpw);
  backtrace_kernel<<<64, 64, 0, stream>>>(vws, bpw, mask, endv, pred);
  loss_reduce<<<1, 64, 0, stream>>>(wsLogZ, wsGold, loss);
}